// Round 8
// baseline (161.471 us; speedup 1.0000x reference)
//
#include <hip/hip_runtime.h>
#include <stdint.h>

#pragma clang fp contract(off)

#define NBOX 8000      // 5x40x40 + 5x80x80
#define NFAST 896      // fast path cap: W<=14, tri mask = 6720 u64 = 52.5 KB
#define WMAX 14
#define NB 16          // grid blocks (<< 256 CUs -> co-resident)
#define MAGIC 0x5EEDF1A6u
typedef unsigned long long u64;

// Agent-coherent relaxed atomics (sc1): cross-XCD safe without cache flushes.
__device__ __forceinline__ u64 aload64(u64* p) {
    return __hip_atomic_load(p, __ATOMIC_RELAXED, __HIP_MEMORY_SCOPE_AGENT);
}
__device__ __forceinline__ void astore64(u64* p, u64 v) {
    __hip_atomic_store(p, v, __ATOMIC_RELAXED, __HIP_MEMORY_SCOPE_AGENT);
}
__device__ __forceinline__ unsigned aload32(unsigned* p) {
    return __hip_atomic_load(p, __ATOMIC_RELAXED, __HIP_MEMORY_SCOPE_AGENT);
}

// pack 4 non-negative u16 coords: x1 | y1<<16 | x2<<32 | y2<<48
__device__ __forceinline__ u64 packBox(int x1, int y1, int x2, int y2) {
    return (u64)(unsigned)(x1 | (y1 << 16)) | ((u64)(unsigned)(x2 | (y2 << 16)) << 32);
}
__device__ __forceinline__ void unpackBox(u64 v, int& x1, int& y1, int& x2, int& y2) {
    unsigned lo = (unsigned)v, hi = (unsigned)(v >> 32);
    x1 = (int)(lo & 0xffffu); y1 = (int)(lo >> 16);
    x2 = (int)(hi & 0xffffu); y2 = (int)(hi >> 16);
}
__device__ __forceinline__ u64 iouBit(u64 rp, int ra, int cx1, int cy1, int cx2, int cy2,
                                      int car, bool cv) {
    int rx1, ry1, rx2, ry2; unpackBox(rp, rx1, ry1, rx2, ry2);
    int iw = max(min(rx2, cx2) - max(rx1, cx1), 0);
    int ih = max(min(ry2, cy2) - max(ry1, cy1), 0);
    int I = __mul24(iw, ih); int P = ra + car;          // exact: ints < 2^23
    return __ballot(cv && (I < P) && (3 * I > P));      // uni>0 && inter>0.5*uni
}

__global__ __launch_bounds__(1024) void k_all(
    const float* __restrict__ outs0, const float* __restrict__ outs1,
    float* __restrict__ out,
    unsigned* __restrict__ ctrl,   // [0]=flag, [16]=producer counter
    u64* __restrict__ triG,        // [6720] tri mask (only cross-block data)
    u64* __restrict__ fbKey, u64* __restrict__ fbBoxC,   // fallback scratch
    u64* __restrict__ sKey2, u64* __restrict__ sBox2, u64* __restrict__ kArr)
{
    // LDS pool with lifetime overlay:
    //  [0,8K)  lkeys   decode..sort     |  tri[6720] (52.5 KB) lives at [0,52.5K)
    //  [8,16K) lbox    decode..sort     |  but is only loaded by block 0 AFTER
    //  [16,24K) sbox_  sort..mask       |  sbox_/sscore are snapshotted to regs.
    //  [24,28K) sscore sort..mask       |
    __shared__ __attribute__((aligned(16))) char pool[53760];   // 52.5 KB
    u64*   tri    = (u64*)pool;
    u64*   lkeys  = (u64*)pool;
    u64*   lbox   = (u64*)(pool + 8192);
    u64*   sbox_  = (u64*)(pool + 16384);
    float* sscore = (float*)(pool + 24576);
    __shared__ u64 keptW[16];
    __shared__ int sCnt;
    const int tid = threadIdx.x, bid = blockIdx.x;
    const int wv = tid >> 6, lane = tid & 63;
    unsigned* flag = ctrl;
    unsigned* slot = ctrl + 16;

    // ---- init gate: block 0 zeroes the producer counter (ws is 0xAA-poisoned) ----
    if (bid == 0 && tid == 0) {
        __hip_atomic_store(slot, 0u, __ATOMIC_RELAXED, __HIP_MEMORY_SCOPE_AGENT);
        __threadfence_block();   // drain vmcnt: slot visible before flag
        __hip_atomic_store(flag, MAGIC, __ATOMIC_RELAXED, __HIP_MEMORY_SCOPE_AGENT);
    }
    if (tid == 0) sCnt = 0;
    __syncthreads();

    // ---- Phase A: every block redundantly decodes ALL boxes into its own LDS ----
    #pragma unroll
    for (int kk = 0; kk < 8; ++kk) {
        int g = (kk << 10) + tid;
        if (g < NBOX) {
            const float* src; int local, i, j; float xps, yps; int pp;
            if (g < 1600) { src = outs0; local = g;        i = local/40; j = local - i*40; xps=16.f; yps=12.f; pp=1600; }
            else          { src = outs1; local = g - 1600; i = local/80; j = local - i*80; xps= 8.f; yps= 6.f; pp=6400; }
            float prob = src[local];
            if (prob > 0.9f) {
                float b1 = src[pp + local], b2 = src[2*pp + local];
                float b3 = src[3*pp + local], b4 = src[4*pp + local];
                // reference: ROW idx i scales x (ii[:,None]); COL idx j scales y
                float c1 = b1*xps + (float)i*xps;
                float c2 = b2*yps + (float)j*yps;
                float X1 = rintf(c1), Y1 = rintf(c2);
                float X2 = rintf(b3*640.0f + c1), Y2 = rintf(b4*480.0f + c2);
                unsigned u = __float_as_uint(prob);
                u ^= (u & 0x80000000u) ? 0xFFFFFFFFu : 0x80000000u;  // monotone map
                u64 key = ((u64)(~u) << 32) | (unsigned)g;  // asc = desc score, asc g
                int pos = atomicAdd(&sCnt, 1);
                if (pos < 1024) {
                    lkeys[pos] = key;
                    lbox[pos]  = packBox((int)X1, (int)Y1, (int)X2, (int)Y2);
                }
            }
        }
    }
    __syncthreads();
    int n = sCnt; if (n > NBOX) n = NBOX;   // identical in every block (same input)

    if (n <= NFAST) {
        const int W = (n + 63) >> 6;
        // ---- zero partition: block 0 owns [0,5n); blocks 1..15 own the tail ----
        if (bid == 0) {
            for (int t = tid; t < 5 * n; t += 1024) out[t] = 0.f;
        } else {
            for (int t = 5 * n + (bid - 1) * 1024 + tid; t < 5 * NBOX; t += 15 * 1024)
                out[t] = 0.f;
        }

        // ---- Phase B: block-local LDS rank-count sort (redundant per block) ----
        if (tid < n) {
            u64 kp = lkeys[tid], bp = lbox[tid];
            int rank = 0;
            for (int q = 0; q < n; ++q) rank += (lkeys[q] < kp) ? 1 : 0;  // LDS broadcast
            sbox_[rank] = bp;
            unsigned u = ~(unsigned)(kp >> 32);
            sscore[rank] = __uint_as_float(u ^ 0x80000000u);
        }
        __syncthreads();
        // snapshot my rank's record to registers (sbox_/sscore die when tri loads)
        float myScore = 0.f; u64 myBoxS = 0;
        if (tid < n) { myScore = sscore[tid]; myBoxS = sbox_[tid]; }

        // ---- Phase C: tri mask, 1/16 of row-quads per block, from local LDS ----
        {
            int nq = (n + 3) >> 2;
            for (int rq = bid * 16 + wv; rq < nq; rq += NB * 16) {
                int r0 = rq << 2;
                int a = r0 >> 6;
                int rowBase = 64 * (a * W - (a * (a - 1)) / 2);
                int Wa = W - a;
                int rr1 = min(r0+1, n-1), rr2 = min(r0+2, n-1), rr3 = min(r0+3, n-1);
                u64 rp0 = sbox_[r0], rp1 = sbox_[rr1], rp2 = sbox_[rr2], rp3 = sbox_[rr3];
                int t1,t2,t3,t4;
                unpackBox(rp0,t1,t2,t3,t4); int ra0 = __mul24(t3-t1, t4-t2);
                unpackBox(rp1,t1,t2,t3,t4); int ra1 = __mul24(t3-t1, t4-t2);
                unpackBox(rp2,t1,t2,t3,t4); int ra2 = __mul24(t3-t1, t4-t2);
                unpackBox(rp3,t1,t2,t3,t4); int ra3 = __mul24(t3-t1, t4-t2);
                for (int k = 0; k < Wa; ++k) {
                    int wcol = a + k;
                    int c = (wcol << 6) + lane;
                    bool cv = c < n;
                    u64 cb = sbox_[cv ? c : (n - 1)];
                    int cx1, cy1, cx2, cy2; unpackBox(cb, cx1, cy1, cx2, cy2);
                    int car = __mul24(cx2 - cx1, cy2 - cy1);
                    u64 wb0 = iouBit(rp0, ra0, cx1, cy1, cx2, cy2, car, cv);
                    u64 wb1 = iouBit(rp1, ra1, cx1, cy1, cx2, cy2, car, cv);
                    u64 wb2 = iouBit(rp2, ra2, cx1, cy1, cx2, cy2, car, cv);
                    u64 wb3 = iouBit(rp3, ra3, cx1, cy1, cx2, cy2, car, cv);
                    if (lane < 4) {
                        int r = r0 + lane;
                        if (r < n) {
                            u64 word = (lane == 0) ? wb0 : (lane == 1) ? wb1
                                     : (lane == 2) ? wb2 : wb3;
                            int b = r & 63;
                            if (wcol == a) {   // diagonal word: clear cols <= r
                                u64 low = (b == 63) ? ~0ULL : ((1ULL << (b + 1)) - 1);
                                word &= ~low;
                            }
                            astore64(&triG[rowBase + b * Wa + k], word);
                        }
                    }
                }
            }
        }
        __syncthreads();   // every wave drains its sc1 stores before signaling

        if (bid != 0) {    // producers: signal and exit (no spin)
            if (tid == 0) {
                while (aload32(flag) != MAGIC) __builtin_amdgcn_s_sleep(1);
                __hip_atomic_fetch_add(slot, 1u, __ATOMIC_RELAXED, __HIP_MEMORY_SCOPE_AGENT);
            }
            return;
        }

        // ---- block 0: wait for 15 producers, bulk-load tri, scalar scan ----
        if (tid == 0) {
            while (aload32(slot) < (unsigned)(NB - 1)) __builtin_amdgcn_s_sleep(1);
        }
        __syncthreads();
        {
            int A = n >> 6, B = n & 63;
            int total = 64 * (A * W - (A * (A - 1)) / 2) + B * (W - A);
            for (int t = tid; t < total; t += 1024) tri[t] = aload64(&triG[t]);
        }
        if (tid < 16) keptW[tid] = 0;
        __syncthreads();

        if (tid < 64 && n > 0) {
            u64 fut = 0;
            if (lane < W) {
                int cnt = n - (lane << 6);
                fut = (cnt >= 64) ? ~0ULL : ((1ULL << cnt) - 1);
            }
            unsigned curLo, curHi;
            {
                u64 c0 = (n >= 64) ? ~0ULL : ((1ULL << n) - 1);
                curLo = (unsigned)__builtin_amdgcn_readfirstlane((int)(unsigned)c0);
                curHi = (unsigned)__builtin_amdgcn_readfirstlane((int)(unsigned)(c0 >> 32));
            }
            int cw = 0;
            for (;;) {
                int base = 64 * (cw * W - (cw * (cw - 1)) / 2);
                int Wa = W - cw;
                unsigned rdLo = 0, rdHi = 0;
                {
                    int r = (cw << 6) + lane;
                    if (r < n) {
                        u64 v = tri[base + lane * Wa];
                        rdLo = (unsigned)v; rdHi = (unsigned)(v >> 32);
                    }
                }
                unsigned khLo = 0, khHi = 0;
                while (curLo | curHi) {
                    int b = curLo ? __builtin_ctz(curLo) : (32 + __builtin_ctz(curHi));
                    unsigned wLo = (unsigned)__builtin_amdgcn_readlane((int)rdLo, b);
                    unsigned wHi = (unsigned)__builtin_amdgcn_readlane((int)rdHi, b);
                    if (curLo) { khLo |= curLo & (0u - curLo); curLo &= curLo - 1; }
                    else       { khHi |= curHi & (0u - curHi); curHi &= curHi - 1; }
                    curLo &= ~wLo; curHi &= ~wHi;
                }
                if (lane == 0) keptW[cw] = ((u64)khHi << 32) | khLo;
                {
                    bool act = (lane > cw) && (lane < W);
                    int off0 = base + (lane - cw);
                    unsigned kl = khLo, kh = khHi;
                    while (kl | kh) {
                        int b = kl ? __builtin_ctz(kl) : (32 + __builtin_ctz(kh));
                        if (kl) kl &= kl - 1; else kh &= kh - 1;
                        if (act) fut &= ~tri[off0 + b * Wa];
                    }
                }
                u64 m = __ballot((fut != 0) && (lane > cw));
                if (!m) break;
                int ncw = (int)__builtin_ctzll(m);
                curLo = (unsigned)__builtin_amdgcn_readlane((int)(unsigned)fut, ncw);
                curHi = (unsigned)__builtin_amdgcn_readlane((int)(unsigned)(fut >> 32), ncw);
                cw = ncw;
            }
        }
        __syncthreads();

        if (tid < n && ((keptW[tid >> 6] >> (tid & 63)) & 1ULL)) {
            int x1, y1, x2, y2; unpackBox(myBoxS, x1, y1, x2, y2);
            out[5*tid+0] = myScore;
            out[5*tid+1] = (float)x1;
            out[5*tid+2] = (float)y1;
            out[5*tid+3] = (float)(x2 - x1);
            out[5*tid+4] = (float)(y2 - y1);
        }
    } else {
        // ===== correctness-only fallback (n > NFAST; never expected) =====
        // blocks 1..15: zero tail (may be empty), signal, exit
        if (bid != 0) {
            for (int t = 5 * n + (bid - 1) * 1024 + tid; t < 5 * NBOX; t += 15 * 1024)
                out[t] = 0.f;
            __syncthreads();
            if (tid == 0) {
                while (aload32(flag) != MAGIC) __builtin_amdgcn_s_sleep(1);
                __hip_atomic_fetch_add(slot, 1u, __ATOMIC_RELAXED, __HIP_MEMORY_SCOPE_AGENT);
            }
            return;
        }
        // block 0: self-sufficient serial path via global scratch (own L2, plain ops)
        int zhi = 5 * n; if (zhi > 5 * NBOX) zhi = 5 * NBOX;
        for (int t = tid; t < zhi; t += 1024) out[t] = 0.f;
        if (tid == 0) sCnt = 0;
        __syncthreads();
        #pragma unroll
        for (int kk = 0; kk < 8; ++kk) {
            int g = (kk << 10) + tid;
            if (g < NBOX) {
                const float* src; int local, i, j; float xps, yps; int pp;
                if (g < 1600) { src = outs0; local = g;        i = local/40; j = local - i*40; xps=16.f; yps=12.f; pp=1600; }
                else          { src = outs1; local = g - 1600; i = local/80; j = local - i*80; xps= 8.f; yps= 6.f; pp=6400; }
                float prob = src[local];
                if (prob > 0.9f) {
                    float b1 = src[pp + local], b2 = src[2*pp + local];
                    float b3 = src[3*pp + local], b4 = src[4*pp + local];
                    float c1 = b1*xps + (float)i*xps;
                    float c2 = b2*yps + (float)j*yps;
                    float X1 = rintf(c1), Y1 = rintf(c2);
                    float X2 = rintf(b3*640.0f + c1), Y2 = rintf(b4*480.0f + c2);
                    unsigned u = __float_as_uint(prob);
                    u ^= (u & 0x80000000u) ? 0xFFFFFFFFu : 0x80000000u;
                    u64 key = ((u64)(~u) << 32) | (unsigned)g;
                    int pos = atomicAdd(&sCnt, 1);
                    if (pos < 8192) {
                        fbKey[pos]  = key;
                        fbBoxC[pos] = packBox((int)X1, (int)Y1, (int)X2, (int)Y2);
                    }
                }
            }
        }
        __syncthreads();
        for (int p = tid; p < n; p += 1024) {
            u64 kp = fbKey[p];
            int rank = 0;
            for (int q = 0; q < n; ++q) rank += (fbKey[q] < kp) ? 1 : 0;
            sKey2[rank] = kp;
            sBox2[rank] = fbBoxC[p];
        }
        __syncthreads();
        if (tid < 64) {
            int kc = 0;
            for (int base2 = 0; base2 < n; base2 += 64) {
                int p = base2 + lane;
                bool in = p < n;
                u64 bp = in ? sBox2[p] : 0, kp2 = in ? sKey2[p] : 0;
                int x1, y1, x2, y2; unpackBox(bp, x1, y1, x2, y2);
                int ar = __mul24(x2 - x1, y2 - y1);
                bool dead = !in;
                for (int k = 0; k < kc; ++k) {
                    int kx1, ky1, kx2, ky2; unpackBox(kArr[k], kx1, ky1, kx2, ky2);
                    int kar = __mul24(kx2 - kx1, ky2 - ky1);
                    int iw = max(min(x2, kx2) - max(x1, kx1), 0);
                    int ih = max(min(y2, ky2) - max(y1, ky1), 0);
                    int I = __mul24(iw, ih); int P = ar + kar;
                    if (I < P && 3 * I > P) dead = true;
                }
                u64 scan = __ballot(!dead);
                while (scan) {
                    int t = (int)__builtin_ctzll(scan);
                    scan &= scan - 1;
                    u64 tb = __shfl(bp, t);
                    if (lane == t) {
                        kArr[kc] = bp;
                        unsigned u = ~(unsigned)(kp2 >> 32);
                        float score = __uint_as_float(u ^ 0x80000000u);
                        out[5*p+0] = score;
                        out[5*p+1] = (float)x1; out[5*p+2] = (float)y1;
                        out[5*p+3] = (float)(x2 - x1); out[5*p+4] = (float)(y2 - y1);
                    }
                    kc++;
                    bool kill = false;
                    if (!dead && lane > t) {
                        int tx1, ty1, tx2, ty2; unpackBox(tb, tx1, ty1, tx2, ty2);
                        int tar = __mul24(tx2 - tx1, ty2 - ty1);
                        int iw = max(min(x2, tx2) - max(x1, tx1), 0);
                        int ih = max(min(y2, ty2) - max(y1, ty1), 0);
                        int I = __mul24(iw, ih); int P = ar + tar;
                        kill = (I < P) && (3 * I > P);
                    }
                    dead = dead || kill;
                    scan &= ~__ballot(dead);
                }
            }
        }
    }
}

extern "C" void kernel_launch(void* const* d_in, const int* in_sizes, int n_in,
                              void* d_out, int out_size, void* d_ws, size_t ws_size,
                              hipStream_t stream) {
    const float* outs0 = (const float*)d_in[0];
    const float* outs1 = (const float*)d_in[1];
    float* out = (float*)d_out;
    char* ws = (char*)d_ws;
    size_t o = 0;
    unsigned* ctrl = (unsigned*)(ws + o); o += 512;
    u64* triG   = (u64*)(ws + o); o += (size_t)6720 * 8;   // 52.5 KB
    u64* fbKey  = (u64*)(ws + o); o += (size_t)8192 * 8;   // 64 KB (fallback)
    u64* fbBoxC = (u64*)(ws + o); o += (size_t)8192 * 8;   // 64 KB (fallback)
    u64* sKey2  = (u64*)(ws + o); o += (size_t)8192 * 8;   // 64 KB (fallback)
    u64* sBox2  = (u64*)(ws + o); o += (size_t)8192 * 8;   // 64 KB (fallback)
    u64* kArr   = (u64*)(ws + o); o += (size_t)8192 * 8;   // 64 KB (fallback)

    hipLaunchKernelGGL(k_all, dim3(NB), dim3(1024), 0, stream,
                       outs0, outs1, out, ctrl, triG,
                       fbKey, fbBoxC, sKey2, sBox2, kArr);
}

// Round 9
// 155.504 us; speedup vs baseline: 1.0384x; 1.0384x over previous
//
#include <hip/hip_runtime.h>
#include <stdint.h>

#pragma clang fp contract(off)

#define NBOX 8000      // 5x40x40 + 5x80x80
#define NFAST 896      // fast path cap: W<=14, tri mask = 6720 u64 = 52.5 KB
#define NB 16          // grid blocks (<< 256 CUs -> co-resident)
#define MAGIC 0x5EEDF1A6u
typedef unsigned long long u64;

// Agent-coherent relaxed atomics (sc1): cross-XCD safe without cache flushes.
__device__ __forceinline__ u64 aload64(u64* p) {
    return __hip_atomic_load(p, __ATOMIC_RELAXED, __HIP_MEMORY_SCOPE_AGENT);
}
__device__ __forceinline__ void astore64(u64* p, u64 v) {
    __hip_atomic_store(p, v, __ATOMIC_RELAXED, __HIP_MEMORY_SCOPE_AGENT);
}
__device__ __forceinline__ unsigned aload32(unsigned* p) {
    return __hip_atomic_load(p, __ATOMIC_RELAXED, __HIP_MEMORY_SCOPE_AGENT);
}

// pack 4 non-negative u16 coords: x1 | y1<<16 | x2<<32 | y2<<48
__device__ __forceinline__ u64 packBox(int x1, int y1, int x2, int y2) {
    return (u64)(unsigned)(x1 | (y1 << 16)) | ((u64)(unsigned)(x2 | (y2 << 16)) << 32);
}
__device__ __forceinline__ void unpackBox(u64 v, int& x1, int& y1, int& x2, int& y2) {
    unsigned lo = (unsigned)v, hi = (unsigned)(v >> 32);
    x1 = (int)(lo & 0xffffu); y1 = (int)(lo >> 16);
    x2 = (int)(hi & 0xffffu); y2 = (int)(hi >> 16);
}
__device__ __forceinline__ u64 iouBit(u64 rp, int ra, int cx1, int cy1, int cx2, int cy2,
                                      int car, bool cv) {
    int rx1, ry1, rx2, ry2; unpackBox(rp, rx1, ry1, rx2, ry2);
    int iw = max(min(rx2, cx2) - max(rx1, cx1), 0);
    int ih = max(min(ry2, cy2) - max(ry1, cy1), 0);
    int I = __mul24(iw, ih); int P = ra + car;          // exact: ints < 2^23
    return __ballot(cv && (I < P) && (3 * I > P));      // uni>0 && inter>0.5*uni
}

__global__ __launch_bounds__(1024) void k_all(
    const float* __restrict__ outs0, const float* __restrict__ outs1,
    float* __restrict__ out,
    unsigned* __restrict__ ctrl,   // [0]=flag, [16]=producer counter
    u64* __restrict__ triG,        // [6720] tri mask (only cross-block data)
    u64* __restrict__ fbKey, u64* __restrict__ fbBoxC,   // fallback scratch
    u64* __restrict__ sKey2, u64* __restrict__ sBox2, u64* __restrict__ kArr)
{
    // LDS overlay: skey[1024] (8K) + sbox[1024] (8K) live through decode..mask;
    // tri[6720] (52.5K) overwrites them in block 0 only, after reg snapshot.
    __shared__ __attribute__((aligned(16))) char pool[53760];
    u64* skey = (u64*)pool;
    u64* sbox = (u64*)(pool + 8192);
    u64* tri  = (u64*)pool;
    __shared__ u64 keptW[16];
    __shared__ int sCnt;
    const int tid = threadIdx.x, bid = blockIdx.x;
    const int wv = tid >> 6, lane = tid & 63;
    unsigned* flag = ctrl;
    unsigned* slot = ctrl + 16;

    // ---- init gate: block 0 zeroes the producer counter (ws is 0xAA-poisoned) ----
    if (bid == 0 && tid == 0) {
        __hip_atomic_store(slot, 0u, __ATOMIC_RELAXED, __HIP_MEMORY_SCOPE_AGENT);
        __threadfence_block();   // drain vmcnt: slot visible before flag
        __hip_atomic_store(flag, MAGIC, __ATOMIC_RELAXED, __HIP_MEMORY_SCOPE_AGENT);
    }
    if (tid == 0) sCnt = 0;
    __syncthreads();

    // ---- Phase A: redundant batched decode; all loads pre-issued (pipelined) ----
    float pb[8], f1[8], f2[8], f3[8], f4[8];
    #pragma unroll
    for (int kk = 0; kk < 8; ++kk) {
        int g = (kk << 10) + tid;
        const float* src; int local, pp;
        if (g < 1600) { src = outs0; local = g;        pp = 1600; }
        else          { src = outs1; local = g - 1600; pp = 6400; }
        int lc = (g < NBOX) ? local : 0;   // clamp pad threads in-bounds
        pb[kk] = src[lc];
        f1[kk] = src[pp + lc];     f2[kk] = src[2*pp + lc];
        f3[kk] = src[3*pp + lc];   f4[kk] = src[4*pp + lc];
    }
    #pragma unroll
    for (int kk = 0; kk < 8; ++kk) {
        int g = (kk << 10) + tid;
        bool lev0 = g < 1600;
        int local = lev0 ? g : g - 1600;
        int i, j; float xps, yps;
        if (lev0) { i = local / 40; j = local - i * 40; xps = 16.f; yps = 12.f; }
        else      { i = local / 80; j = local - i * 80; xps =  8.f; yps =  6.f; }
        float prob = pb[kk];
        bool valid = (g < NBOX) && (prob > 0.9f);
        u64 key = 0, bpk = 0;
        if (valid) {
            // reference: ROW idx i scales x (ii[:,None]); COL idx j scales y
            float c1 = f1[kk]*xps + (float)i*xps;
            float c2 = f2[kk]*yps + (float)j*yps;
            float X1 = rintf(c1), Y1 = rintf(c2);
            float X2 = rintf(f3[kk]*640.0f + c1), Y2 = rintf(f4[kk]*480.0f + c2);
            unsigned u = __float_as_uint(prob);
            u ^= (u & 0x80000000u) ? 0xFFFFFFFFu : 0x80000000u;  // monotone map
            key = ((u64)(~u) << 32) | (unsigned)g;  // asc = desc score, asc g
            bpk = packBox((int)X1, (int)Y1, (int)X2, (int)Y2);
        }
        // per-wave ballot compaction: one LDS atomic per wave, not per thread
        u64 bal = __ballot(valid);
        int cnt = (int)__popcll(bal);
        int wbase = 0;
        if (lane == 0) wbase = cnt ? atomicAdd(&sCnt, cnt) : 0;
        wbase = __shfl(wbase, 0);
        int pos = wbase + (int)__popcll(bal & ((1ULL << lane) - 1ULL));
        if (valid && pos < 1024) { skey[pos] = key; sbox[pos] = bpk; }
    }
    __syncthreads();
    int n = sCnt; if (n > NBOX) n = NBOX;   // identical in every block (same input)

    if (n <= NFAST) {
        const int W = (n + 63) >> 6;
        // ---- zero partition: block 0 owns [0,5n); blocks 1..15 own the tail ----
        if (bid == 0) {
            for (int t = tid; t < 5 * n; t += 1024) out[t] = 0.f;
        } else {
            for (int t = 5 * n + (bid - 1) * 1024 + tid; t < 5 * NBOX; t += 15 * 1024)
                out[t] = 0.f;
        }
        // ---- Phase B: block-local bitonic sort (key + box payload) ----
        if (tid >= n) { skey[tid] = ~0ULL; sbox[tid] = 0; }
        __syncthreads();
        for (int k = 2; k <= 1024; k <<= 1) {
            for (int j = k >> 1; j > 0; j >>= 1) {
                int ixj = tid ^ j;
                if (ixj > tid) {
                    u64 a = skey[tid], b = skey[ixj];
                    bool up = ((tid & k) == 0);
                    if ((a > b) == up) {
                        skey[tid] = b; skey[ixj] = a;
                        u64 ba = sbox[tid], bb = sbox[ixj];
                        sbox[tid] = bb; sbox[ixj] = ba;
                    }
                }
                __syncthreads();
            }
        }
        // snapshot my rank's record to registers (sbox/skey die when tri loads)
        float myScore = 0.f; u64 myBoxS = 0;
        if (tid < n) {
            u64 key = skey[tid];
            unsigned u = ~(unsigned)(key >> 32);
            myScore = __uint_as_float(u ^ 0x80000000u);
            myBoxS = sbox[tid];
        }

        // ---- Phase C: tri mask, 1/16 of row-quads per block, from local LDS ----
        {
            int nq = (n + 3) >> 2;
            for (int rq = bid * 16 + wv; rq < nq; rq += NB * 16) {
                int r0 = rq << 2;
                int a = r0 >> 6;
                int rowBase = 64 * (a * W - (a * (a - 1)) / 2);
                int Wa = W - a;
                int rr1 = min(r0+1, n-1), rr2 = min(r0+2, n-1), rr3 = min(r0+3, n-1);
                u64 rp0 = sbox[r0], rp1 = sbox[rr1], rp2 = sbox[rr2], rp3 = sbox[rr3];
                int t1,t2,t3,t4;
                unpackBox(rp0,t1,t2,t3,t4); int ra0 = __mul24(t3-t1, t4-t2);
                unpackBox(rp1,t1,t2,t3,t4); int ra1 = __mul24(t3-t1, t4-t2);
                unpackBox(rp2,t1,t2,t3,t4); int ra2 = __mul24(t3-t1, t4-t2);
                unpackBox(rp3,t1,t2,t3,t4); int ra3 = __mul24(t3-t1, t4-t2);
                for (int k = 0; k < Wa; ++k) {
                    int wcol = a + k;
                    int c = (wcol << 6) + lane;
                    bool cv = c < n;
                    u64 cb = sbox[cv ? c : (n - 1)];
                    int cx1, cy1, cx2, cy2; unpackBox(cb, cx1, cy1, cx2, cy2);
                    int car = __mul24(cx2 - cx1, cy2 - cy1);
                    u64 wb0 = iouBit(rp0, ra0, cx1, cy1, cx2, cy2, car, cv);
                    u64 wb1 = iouBit(rp1, ra1, cx1, cy1, cx2, cy2, car, cv);
                    u64 wb2 = iouBit(rp2, ra2, cx1, cy1, cx2, cy2, car, cv);
                    u64 wb3 = iouBit(rp3, ra3, cx1, cy1, cx2, cy2, car, cv);
                    if (lane < 4) {
                        int r = r0 + lane;
                        if (r < n) {
                            u64 word = (lane == 0) ? wb0 : (lane == 1) ? wb1
                                     : (lane == 2) ? wb2 : wb3;
                            int b = r & 63;
                            if (wcol == a) {   // diagonal word: clear cols <= r
                                u64 low = (b == 63) ? ~0ULL : ((1ULL << (b + 1)) - 1);
                                word &= ~low;
                            }
                            astore64(&triG[rowBase + b * Wa + k], word);
                        }
                    }
                }
            }
        }
        __syncthreads();   // drains vmcnt: sc1 tri stores visible before signal

        if (bid != 0) {    // producers: signal and exit
            if (tid == 0) {
                while (aload32(flag) != MAGIC) __builtin_amdgcn_s_sleep(1);
                __hip_atomic_fetch_add(slot, 1u, __ATOMIC_RELAXED, __HIP_MEMORY_SCOPE_AGENT);
            }
            return;
        }

        // ---- block 0: wait for 15 producers, bulk-load tri, scalar scan ----
        if (tid == 0) {
            while (aload32(slot) < (unsigned)(NB - 1)) __builtin_amdgcn_s_sleep(1);
        }
        __syncthreads();
        {
            int A = n >> 6, B = n & 63;
            int total = 64 * (A * W - (A * (A - 1)) / 2) + B * (W - A);
            for (int t = tid; t < total; t += 1024) tri[t] = aload64(&triG[t]);
        }
        if (tid < 16) keptW[tid] = 0;
        __syncthreads();

        if (tid < 64 && n > 0) {
            u64 fut = 0;
            if (lane < W) {
                int cnt = n - (lane << 6);
                fut = (cnt >= 64) ? ~0ULL : ((1ULL << cnt) - 1);
            }
            unsigned curLo, curHi;
            {
                u64 c0 = (n >= 64) ? ~0ULL : ((1ULL << n) - 1);
                curLo = (unsigned)__builtin_amdgcn_readfirstlane((int)(unsigned)c0);
                curHi = (unsigned)__builtin_amdgcn_readfirstlane((int)(unsigned)(c0 >> 32));
            }
            int cw = 0;
            for (;;) {
                int base = 64 * (cw * W - (cw * (cw - 1)) / 2);
                int Wa = W - cw;
                unsigned rdLo = 0, rdHi = 0;
                {
                    int r = (cw << 6) + lane;
                    if (r < n) {
                        u64 v = tri[base + lane * Wa];
                        rdLo = (unsigned)v; rdHi = (unsigned)(v >> 32);
                    }
                }
                unsigned khLo = 0, khHi = 0;
                while (curLo | curHi) {
                    int b = curLo ? __builtin_ctz(curLo) : (32 + __builtin_ctz(curHi));
                    unsigned wLo = (unsigned)__builtin_amdgcn_readlane((int)rdLo, b);
                    unsigned wHi = (unsigned)__builtin_amdgcn_readlane((int)rdHi, b);
                    if (curLo) { khLo |= curLo & (0u - curLo); curLo &= curLo - 1; }
                    else       { khHi |= curHi & (0u - curHi); curHi &= curHi - 1; }
                    curLo &= ~wLo; curHi &= ~wHi;
                }
                if (lane == 0) keptW[cw] = ((u64)khHi << 32) | khLo;
                {
                    bool act = (lane > cw) && (lane < W);
                    int off0 = base + (lane - cw);
                    unsigned kl = khLo, kh = khHi;
                    while (kl | kh) {
                        int b = kl ? __builtin_ctz(kl) : (32 + __builtin_ctz(kh));
                        if (kl) kl &= kl - 1; else kh &= kh - 1;
                        if (act) fut &= ~tri[off0 + b * Wa];
                    }
                }
                u64 m = __ballot((fut != 0) && (lane > cw));
                if (!m) break;
                int ncw = (int)__builtin_ctzll(m);
                curLo = (unsigned)__builtin_amdgcn_readlane((int)(unsigned)fut, ncw);
                curHi = (unsigned)__builtin_amdgcn_readlane((int)(unsigned)(fut >> 32), ncw);
                cw = ncw;
            }
        }
        __syncthreads();

        if (tid < n && ((keptW[tid >> 6] >> (tid & 63)) & 1ULL)) {
            int x1, y1, x2, y2; unpackBox(myBoxS, x1, y1, x2, y2);
            out[5*tid+0] = myScore;
            out[5*tid+1] = (float)x1;
            out[5*tid+2] = (float)y1;
            out[5*tid+3] = (float)(x2 - x1);
            out[5*tid+4] = (float)(y2 - y1);
        }
    } else {
        // ===== correctness-only fallback (n > NFAST; never expected) =====
        if (bid != 0) {
            for (int t = 5 * n + (bid - 1) * 1024 + tid; t < 5 * NBOX; t += 15 * 1024)
                out[t] = 0.f;
            __syncthreads();
            if (tid == 0) {
                while (aload32(flag) != MAGIC) __builtin_amdgcn_s_sleep(1);
                __hip_atomic_fetch_add(slot, 1u, __ATOMIC_RELAXED, __HIP_MEMORY_SCOPE_AGENT);
            }
            return;
        }
        // block 0: self-sufficient serial path via global scratch (own L2)
        int zhi = 5 * n; if (zhi > 5 * NBOX) zhi = 5 * NBOX;
        for (int t = tid; t < zhi; t += 1024) out[t] = 0.f;
        if (tid == 0) sCnt = 0;
        __syncthreads();
        #pragma unroll
        for (int kk = 0; kk < 8; ++kk) {
            int g = (kk << 10) + tid;
            if (g < NBOX) {
                const float* src; int local, i, j; float xps, yps; int pp;
                if (g < 1600) { src = outs0; local = g;        i = local/40; j = local - i*40; xps=16.f; yps=12.f; pp=1600; }
                else          { src = outs1; local = g - 1600; i = local/80; j = local - i*80; xps= 8.f; yps= 6.f; pp=6400; }
                float prob = src[local];
                if (prob > 0.9f) {
                    float b1 = src[pp + local], b2 = src[2*pp + local];
                    float b3 = src[3*pp + local], b4 = src[4*pp + local];
                    float c1 = b1*xps + (float)i*xps;
                    float c2 = b2*yps + (float)j*yps;
                    float X1 = rintf(c1), Y1 = rintf(c2);
                    float X2 = rintf(b3*640.0f + c1), Y2 = rintf(b4*480.0f + c2);
                    unsigned u = __float_as_uint(prob);
                    u ^= (u & 0x80000000u) ? 0xFFFFFFFFu : 0x80000000u;
                    u64 key = ((u64)(~u) << 32) | (unsigned)g;
                    int pos = atomicAdd(&sCnt, 1);
                    if (pos < 8192) {
                        fbKey[pos]  = key;
                        fbBoxC[pos] = packBox((int)X1, (int)Y1, (int)X2, (int)Y2);
                    }
                }
            }
        }
        __syncthreads();
        for (int p = tid; p < n; p += 1024) {
            u64 kp = fbKey[p];
            int rank = 0;
            for (int q = 0; q < n; ++q) rank += (fbKey[q] < kp) ? 1 : 0;
            sKey2[rank] = kp;
            sBox2[rank] = fbBoxC[p];
        }
        __syncthreads();
        if (tid < 64) {
            int kc = 0;
            for (int base2 = 0; base2 < n; base2 += 64) {
                int p = base2 + lane;
                bool in = p < n;
                u64 bp = in ? sBox2[p] : 0, kp2 = in ? sKey2[p] : 0;
                int x1, y1, x2, y2; unpackBox(bp, x1, y1, x2, y2);
                int ar = __mul24(x2 - x1, y2 - y1);
                bool dead = !in;
                for (int k = 0; k < kc; ++k) {
                    int kx1, ky1, kx2, ky2; unpackBox(kArr[k], kx1, ky1, kx2, ky2);
                    int kar = __mul24(kx2 - kx1, ky2 - ky1);
                    int iw = max(min(x2, kx2) - max(x1, kx1), 0);
                    int ih = max(min(y2, ky2) - max(y1, ky1), 0);
                    int I = __mul24(iw, ih); int P = ar + kar;
                    if (I < P && 3 * I > P) dead = true;
                }
                u64 scan = __ballot(!dead);
                while (scan) {
                    int t = (int)__builtin_ctzll(scan);
                    scan &= scan - 1;
                    u64 tb = __shfl(bp, t);
                    if (lane == t) {
                        kArr[kc] = bp;
                        unsigned u = ~(unsigned)(kp2 >> 32);
                        float score = __uint_as_float(u ^ 0x80000000u);
                        out[5*p+0] = score;
                        out[5*p+1] = (float)x1; out[5*p+2] = (float)y1;
                        out[5*p+3] = (float)(x2 - x1); out[5*p+4] = (float)(y2 - y1);
                    }
                    kc++;
                    bool kill = false;
                    if (!dead && lane > t) {
                        int tx1, ty1, tx2, ty2; unpackBox(tb, tx1, ty1, tx2, ty2);
                        int tar = __mul24(tx2 - tx1, ty2 - ty1);
                        int iw = max(min(x2, tx2) - max(x1, tx1), 0);
                        int ih = max(min(y2, ty2) - max(y1, ty1), 0);
                        int I = __mul24(iw, ih); int P = ar + tar;
                        kill = (I < P) && (3 * I > P);
                    }
                    dead = dead || kill;
                    scan &= ~__ballot(dead);
                }
            }
        }
    }
}

extern "C" void kernel_launch(void* const* d_in, const int* in_sizes, int n_in,
                              void* d_out, int out_size, void* d_ws, size_t ws_size,
                              hipStream_t stream) {
    const float* outs0 = (const float*)d_in[0];
    const float* outs1 = (const float*)d_in[1];
    float* out = (float*)d_out;
    char* ws = (char*)d_ws;
    size_t o = 0;
    unsigned* ctrl = (unsigned*)(ws + o); o += 512;
    u64* triG   = (u64*)(ws + o); o += (size_t)6720 * 8;   // 52.5 KB
    u64* fbKey  = (u64*)(ws + o); o += (size_t)8192 * 8;   // 64 KB (fallback)
    u64* fbBoxC = (u64*)(ws + o); o += (size_t)8192 * 8;   // 64 KB (fallback)
    u64* sKey2  = (u64*)(ws + o); o += (size_t)8192 * 8;   // 64 KB (fallback)
    u64* sBox2  = (u64*)(ws + o); o += (size_t)8192 * 8;   // 64 KB (fallback)
    u64* kArr   = (u64*)(ws + o); o += (size_t)8192 * 8;   // 64 KB (fallback)

    hipLaunchKernelGGL(k_all, dim3(NB), dim3(1024), 0, stream,
                       outs0, outs1, out, ctrl, triG,
                       fbKey, fbBoxC, sKey2, sBox2, kArr);
}

// Round 10
// 140.137 us; speedup vs baseline: 1.1522x; 1.1097x over previous
//
#include <hip/hip_runtime.h>
#include <stdint.h>

#pragma clang fp contract(off)

#define NBOX 8000      // 5x40x40 + 5x80x80
#define NFAST 896      // fast path cap: W<=14, tri mask = 6720 u64 = 52.5 KB
#define NB 16          // grid blocks (<< 256 CUs -> co-resident)
#define MAGIC 0x5EEDF1A6u
typedef unsigned long long u64;

// Agent-coherent relaxed atomics (sc1): cross-XCD safe without cache flushes.
__device__ __forceinline__ u64 aload64(u64* p) {
    return __hip_atomic_load(p, __ATOMIC_RELAXED, __HIP_MEMORY_SCOPE_AGENT);
}
__device__ __forceinline__ void astore64(u64* p, u64 v) {
    __hip_atomic_store(p, v, __ATOMIC_RELAXED, __HIP_MEMORY_SCOPE_AGENT);
}
__device__ __forceinline__ unsigned aload32(unsigned* p) {
    return __hip_atomic_load(p, __ATOMIC_RELAXED, __HIP_MEMORY_SCOPE_AGENT);
}
__device__ __forceinline__ unsigned aadd32(unsigned* p, unsigned v) {
    return __hip_atomic_fetch_add(p, v, __ATOMIC_RELAXED, __HIP_MEMORY_SCOPE_AGENT);
}

// pack 4 non-negative u16 coords: x1 | y1<<16 | x2<<32 | y2<<48
__device__ __forceinline__ u64 packBox(int x1, int y1, int x2, int y2) {
    return (u64)(unsigned)(x1 | (y1 << 16)) | ((u64)(unsigned)(x2 | (y2 << 16)) << 32);
}
__device__ __forceinline__ void unpackBox(u64 v, int& x1, int& y1, int& x2, int& y2) {
    unsigned lo = (unsigned)v, hi = (unsigned)(v >> 32);
    x1 = (int)(lo & 0xffffu); y1 = (int)(lo >> 16);
    x2 = (int)(hi & 0xffffu); y2 = (int)(hi >> 16);
}
__device__ __forceinline__ u64 iouBit(u64 rp, int ra, int cx1, int cy1, int cx2, int cy2,
                                      int car, bool cv) {
    int rx1, ry1, rx2, ry2; unpackBox(rp, rx1, ry1, rx2, ry2);
    int iw = max(min(rx2, cx2) - max(rx1, cx1), 0);
    int ih = max(min(ry2, cy2) - max(ry1, cy1), 0);
    int I = __mul24(iw, ih); int P = ra + car;          // exact: ints < 2^23
    return __ballot(cv && (I < P) && (3 * I > P));      // uni>0 && inter>0.5*uni
}

__global__ __launch_bounds__(1024) void k_all(
    const float* __restrict__ outs0, const float* __restrict__ outs1,
    float* __restrict__ out,
    unsigned* __restrict__ ctrl,   // [0]=flag,[16]=bar0,[32]=bar1,[48]=sig,[64]=gcnt
    u64* __restrict__ gKey, u64* __restrict__ gBox,      // [8192] compacted (unsorted)
    u64* __restrict__ sKey, u64* __restrict__ sBox,      // [1024] sorted
    u64* __restrict__ triG,                              // [6720] tri mask
    u64* __restrict__ fbKey, u64* __restrict__ fbBoxC,   // fallback scratch
    u64* __restrict__ sKey2, u64* __restrict__ sBox2, u64* __restrict__ kArr)
{
    // LDS overlay: lkey[896]@0 (7K) + lbox[896]@7168 (7K) in phase B;
    // sorted-box copy reuses lkey@0 in phase C; tri[6720] (52.5K) @0 in phase D.
    __shared__ __attribute__((aligned(16))) char pool[53760];
    u64* lkey = (u64*)pool;
    u64* lbox = (u64*)(pool + 7168);
    u64* tri  = (u64*)pool;
    __shared__ int cnt64[64];
    __shared__ int sCnt, sBase, sN;
    __shared__ u64 keptW[16];
    const int tid = threadIdx.x, bid = blockIdx.x;
    const int wv = tid >> 6, lane = tid & 63;
    unsigned* flag = ctrl;
    unsigned* bar0 = ctrl + 16;
    unsigned* bar1 = ctrl + 32;
    unsigned* sig  = ctrl + 48;
    unsigned* gcnt = ctrl + 64;

    // ---- init gate: block 0 zeroes control words (ws is 0xAA-poisoned) ----
    if (bid == 0 && tid == 0) {
        __hip_atomic_store(bar0, 0u, __ATOMIC_RELAXED, __HIP_MEMORY_SCOPE_AGENT);
        __hip_atomic_store(bar1, 0u, __ATOMIC_RELAXED, __HIP_MEMORY_SCOPE_AGENT);
        __hip_atomic_store(sig,  0u, __ATOMIC_RELAXED, __HIP_MEMORY_SCOPE_AGENT);
        __hip_atomic_store(gcnt, 0u, __ATOMIC_RELAXED, __HIP_MEMORY_SCOPE_AGENT);
        __threadfence_block();   // drain vmcnt: slots visible before flag
        __hip_atomic_store(flag, MAGIC, __ATOMIC_RELAXED, __HIP_MEMORY_SCOPE_AGENT);
    }
    if (tid == 0) { sCnt = 0; sBase = 0; }
    __syncthreads();

    // ---- Phase A: distributed decode, one box per thread (blocks 0..7) ----
    bool valid = false; u64 myKey = 0, myPk = 0;
    {
        int g = (bid << 10) + tid;
        if (bid < 8 && g < NBOX) {
            const float* src; int local, i, j; float xps, yps; int pp;
            if (g < 1600) { src = outs0; local = g;        i = local/40; j = local - i*40; xps=16.f; yps=12.f; pp=1600; }
            else          { src = outs1; local = g - 1600; i = local/80; j = local - i*80; xps= 8.f; yps= 6.f; pp=6400; }
            float prob = src[local];
            if (prob > 0.9f) {
                float b1 = src[pp + local], b2 = src[2*pp + local];
                float b3 = src[3*pp + local], b4 = src[4*pp + local];
                // reference: ROW idx i scales x (ii[:,None]); COL idx j scales y
                float c1 = b1*xps + (float)i*xps;
                float c2 = b2*yps + (float)j*yps;
                float X1 = rintf(c1), Y1 = rintf(c2);
                float X2 = rintf(b3*640.0f + c1), Y2 = rintf(b4*480.0f + c2);
                unsigned u = __float_as_uint(prob);
                u ^= (u & 0x80000000u) ? 0xFFFFFFFFu : 0x80000000u;  // monotone map
                myKey = ((u64)(~u) << 32) | (unsigned)g;  // asc = desc score, asc g
                myPk = packBox((int)X1, (int)Y1, (int)X2, (int)Y2);
                valid = true;
            }
        }
    }
    // block-local compaction: LDS atomic per wave, one device atomic per block
    u64 bal = __ballot(valid);
    int wcnt = (int)__popcll(bal);
    int wbase = 0;
    if (lane == 0 && wcnt) wbase = atomicAdd(&sCnt, wcnt);
    wbase = __shfl(wbase, 0);
    int posl = wbase + (int)__popcll(bal & ((1ULL << lane) - 1ULL));

    if (tid == 0) {  // gate: init done before any ctrl/global-ws use
        while (aload32(flag) != MAGIC) __builtin_amdgcn_s_sleep(1);
    }
    __syncthreads();
    if (tid == 0 && sCnt) sBase = (int)aadd32(gcnt, (unsigned)sCnt);
    __syncthreads();
    if (valid) {
        int pos = sBase + posl;
        astore64(&gKey[pos], myKey);
        astore64(&gBox[pos], myPk);
    }

    // ---- grid barrier 0 ----
    __syncthreads();
    if (tid == 0) {
        aadd32(bar0, 1u);
        while (aload32(bar0) < NB) __builtin_amdgcn_s_sleep(1);
        sN = (int)aload32(gcnt);
    }
    __syncthreads();
    int n = sN; if (n > NBOX) n = NBOX;

    if (n <= NFAST) {
        const int W = (n + 63) >> 6;
        // ---- zero partition: block 0 owns [0,5n); blocks 1..15 own the tail ----
        if (bid == 0) {
            for (int t = tid; t < 5 * n; t += 1024) out[t] = 0.f;
        } else {
            for (int t = 5 * n + ((bid - 1) << 10) + tid; t < 5 * NBOX; t += 15 * 1024)
                out[t] = 0.f;
        }

        // ---- Phase B: bulk keys+boxes -> LDS; rank-count own p-slice only ----
        for (int t = tid; t < n; t += 1024) lkey[t] = aload64(&gKey[t]);
        for (int t = tid; t < n; t += 1024) lbox[t] = aload64(&gBox[t]);
        if (tid < 64) cnt64[tid] = 0;
        __syncthreads();
        int pc = (n + 15) >> 4;          // p's per block, <= 56
        int pl = tid >> 4, qs = tid & 15;
        int p = bid * pc + pl;
        bool pv = (pl < pc) && (p < n);
        if (pv) {
            u64 kp = lkey[p];
            int qc = (n + 15) >> 4;
            int qlo = qs * qc, qhi = min(qlo + qc, n);
            int c2 = 0;
            for (int q = qlo; q < qhi; ++q) c2 += (lkey[q] < kp) ? 1 : 0;
            if (c2) atomicAdd(&cnt64[pl], c2);
        }
        __syncthreads();
        if (pv && qs == 0) {
            int rank = cnt64[pl];        // keys unique -> exact rank
            astore64(&sKey[rank], lkey[p]);
            astore64(&sBox[rank], lbox[p]);
        }

        // ---- grid barrier 1 ----
        __syncthreads();
        if (tid == 0) {
            aadd32(bar1, 1u);
            while (aload32(bar1) < NB) __builtin_amdgcn_s_sleep(1);
        }
        __syncthreads();

        // ---- Phase C: sorted boxes -> LDS; tri mask 1 row-quad per wave ----
        u64* sb = lkey;   // reuse
        for (int t = tid; t < n; t += 1024) sb[t] = aload64(&sBox[t]);
        __syncthreads();
        u64 myBoxS = 0;
        if (bid == 0 && tid < n) myBoxS = sb[tid];   // snapshot before tri overlay
        {
            int nq = (n + 3) >> 2;
            for (int rq = bid * 16 + wv; rq < nq; rq += NB * 16) {
                int r0 = rq << 2;
                int a = r0 >> 6;
                int rowBase = 64 * (a * W - (a * (a - 1)) / 2);
                int Wa = W - a;
                int rr1 = min(r0+1, n-1), rr2 = min(r0+2, n-1), rr3 = min(r0+3, n-1);
                u64 rp0 = sb[r0], rp1 = sb[rr1], rp2 = sb[rr2], rp3 = sb[rr3];
                int t1,t2,t3,t4;
                unpackBox(rp0,t1,t2,t3,t4); int ra0 = __mul24(t3-t1, t4-t2);
                unpackBox(rp1,t1,t2,t3,t4); int ra1 = __mul24(t3-t1, t4-t2);
                unpackBox(rp2,t1,t2,t3,t4); int ra2 = __mul24(t3-t1, t4-t2);
                unpackBox(rp3,t1,t2,t3,t4); int ra3 = __mul24(t3-t1, t4-t2);
                for (int k = 0; k < Wa; ++k) {
                    int wcol = a + k;
                    int c = (wcol << 6) + lane;
                    bool cv = c < n;
                    u64 cb = sb[cv ? c : (n - 1)];
                    int cx1, cy1, cx2, cy2; unpackBox(cb, cx1, cy1, cx2, cy2);
                    int car = __mul24(cx2 - cx1, cy2 - cy1);
                    u64 wb0 = iouBit(rp0, ra0, cx1, cy1, cx2, cy2, car, cv);
                    u64 wb1 = iouBit(rp1, ra1, cx1, cy1, cx2, cy2, car, cv);
                    u64 wb2 = iouBit(rp2, ra2, cx1, cy1, cx2, cy2, car, cv);
                    u64 wb3 = iouBit(rp3, ra3, cx1, cy1, cx2, cy2, car, cv);
                    if (lane < 4) {
                        int r = r0 + lane;
                        if (r < n) {
                            u64 word = (lane == 0) ? wb0 : (lane == 1) ? wb1
                                     : (lane == 2) ? wb2 : wb3;
                            int b = r & 63;
                            if (wcol == a) {   // diagonal word: clear cols <= r
                                u64 low = (b == 63) ? ~0ULL : ((1ULL << (b + 1)) - 1);
                                word &= ~low;
                            }
                            astore64(&triG[rowBase + b * Wa + k], word);
                        }
                    }
                }
            }
        }
        __syncthreads();   // all waves drain sc1 tri stores before signal

        if (bid != 0) {    // producers: signal and exit
            if (tid == 0) aadd32(sig, 1u);
            return;
        }

        // ---- block 0: wait producers, bulk-load tri, scalar scan, write ----
        if (tid == 0) {
            while (aload32(sig) < (unsigned)(NB - 1)) __builtin_amdgcn_s_sleep(1);
        }
        __syncthreads();
        {
            int A = n >> 6, B = n & 63;
            int total = 64 * (A * W - (A * (A - 1)) / 2) + B * (W - A);
            for (int t = tid; t < total; t += 1024) tri[t] = aload64(&triG[t]);
        }
        if (tid < 16) keptW[tid] = 0;
        __syncthreads();

        if (tid < 64 && n > 0) {
            u64 fut = 0;
            if (lane < W) {
                int cnt = n - (lane << 6);
                fut = (cnt >= 64) ? ~0ULL : ((1ULL << cnt) - 1);
            }
            unsigned curLo, curHi;
            {
                u64 c0 = (n >= 64) ? ~0ULL : ((1ULL << n) - 1);
                curLo = (unsigned)__builtin_amdgcn_readfirstlane((int)(unsigned)c0);
                curHi = (unsigned)__builtin_amdgcn_readfirstlane((int)(unsigned)(c0 >> 32));
            }
            int cw = 0;
            for (;;) {
                int base = 64 * (cw * W - (cw * (cw - 1)) / 2);
                int Wa = W - cw;
                unsigned rdLo = 0, rdHi = 0;
                {
                    int r = (cw << 6) + lane;
                    if (r < n) {
                        u64 v = tri[base + lane * Wa];
                        rdLo = (unsigned)v; rdHi = (unsigned)(v >> 32);
                    }
                }
                unsigned khLo = 0, khHi = 0;
                while (curLo | curHi) {
                    int b = curLo ? __builtin_ctz(curLo) : (32 + __builtin_ctz(curHi));
                    unsigned wLo = (unsigned)__builtin_amdgcn_readlane((int)rdLo, b);
                    unsigned wHi = (unsigned)__builtin_amdgcn_readlane((int)rdHi, b);
                    if (curLo) { khLo |= curLo & (0u - curLo); curLo &= curLo - 1; }
                    else       { khHi |= curHi & (0u - curHi); curHi &= curHi - 1; }
                    curLo &= ~wLo; curHi &= ~wHi;
                }
                if (lane == 0) keptW[cw] = ((u64)khHi << 32) | khLo;
                {
                    bool act = (lane > cw) && (lane < W);
                    int off0 = base + (lane - cw);
                    unsigned kl = khLo, kh = khHi;
                    while (kl | kh) {
                        int b = kl ? __builtin_ctz(kl) : (32 + __builtin_ctz(kh));
                        if (kl) kl &= kl - 1; else kh &= kh - 1;
                        if (act) fut &= ~tri[off0 + b * Wa];
                    }
                }
                u64 m = __ballot((fut != 0) && (lane > cw));
                if (!m) break;
                int ncw = (int)__builtin_ctzll(m);
                curLo = (unsigned)__builtin_amdgcn_readlane((int)(unsigned)fut, ncw);
                curHi = (unsigned)__builtin_amdgcn_readlane((int)(unsigned)(fut >> 32), ncw);
                cw = ncw;
            }
        }
        __syncthreads();

        if (tid < n && ((keptW[tid >> 6] >> (tid & 63)) & 1ULL)) {
            u64 key = aload64(&sKey[tid]);
            unsigned u = ~(unsigned)(key >> 32);
            float score = __uint_as_float(u ^ 0x80000000u);
            int x1, y1, x2, y2; unpackBox(myBoxS, x1, y1, x2, y2);
            out[5*tid+0] = score;
            out[5*tid+1] = (float)x1;
            out[5*tid+2] = (float)y1;
            out[5*tid+3] = (float)(x2 - x1);
            out[5*tid+4] = (float)(y2 - y1);
        }
    } else {
        // ===== correctness-only fallback (n > NFAST; never expected) =====
        if (bid != 0) {
            for (int t = 5 * n + ((bid - 1) << 10) + tid; t < 5 * NBOX; t += 15 * 1024)
                out[t] = 0.f;
            __syncthreads();
            if (tid == 0) aadd32(sig, 1u);
            return;
        }
        // block 0: self-sufficient serial path via global scratch (own L2)
        int zhi = 5 * n; if (zhi > 5 * NBOX) zhi = 5 * NBOX;
        for (int t = tid; t < zhi; t += 1024) out[t] = 0.f;
        if (tid == 0) sCnt = 0;
        __syncthreads();
        #pragma unroll
        for (int kk = 0; kk < 8; ++kk) {
            int g = (kk << 10) + tid;
            if (g < NBOX) {
                const float* src; int local, i, j; float xps, yps; int pp;
                if (g < 1600) { src = outs0; local = g;        i = local/40; j = local - i*40; xps=16.f; yps=12.f; pp=1600; }
                else          { src = outs1; local = g - 1600; i = local/80; j = local - i*80; xps= 8.f; yps= 6.f; pp=6400; }
                float prob = src[local];
                if (prob > 0.9f) {
                    float b1 = src[pp + local], b2 = src[2*pp + local];
                    float b3 = src[3*pp + local], b4 = src[4*pp + local];
                    float c1 = b1*xps + (float)i*xps;
                    float c2 = b2*yps + (float)j*yps;
                    float X1 = rintf(c1), Y1 = rintf(c2);
                    float X2 = rintf(b3*640.0f + c1), Y2 = rintf(b4*480.0f + c2);
                    unsigned u = __float_as_uint(prob);
                    u ^= (u & 0x80000000u) ? 0xFFFFFFFFu : 0x80000000u;
                    u64 key = ((u64)(~u) << 32) | (unsigned)g;
                    int pos = atomicAdd(&sCnt, 1);
                    if (pos < 8192) {
                        fbKey[pos]  = key;
                        fbBoxC[pos] = packBox((int)X1, (int)Y1, (int)X2, (int)Y2);
                    }
                }
            }
        }
        __syncthreads();
        for (int p = tid; p < n; p += 1024) {
            u64 kp = fbKey[p];
            int rank = 0;
            for (int q = 0; q < n; ++q) rank += (fbKey[q] < kp) ? 1 : 0;
            sKey2[rank] = kp;
            sBox2[rank] = fbBoxC[p];
        }
        __syncthreads();
        if (tid < 64) {
            int kc = 0;
            for (int base2 = 0; base2 < n; base2 += 64) {
                int p = base2 + lane;
                bool in = p < n;
                u64 bp = in ? sBox2[p] : 0, kp2 = in ? sKey2[p] : 0;
                int x1, y1, x2, y2; unpackBox(bp, x1, y1, x2, y2);
                int ar = __mul24(x2 - x1, y2 - y1);
                bool dead = !in;
                for (int k = 0; k < kc; ++k) {
                    int kx1, ky1, kx2, ky2; unpackBox(kArr[k], kx1, ky1, kx2, ky2);
                    int kar = __mul24(kx2 - kx1, ky2 - ky1);
                    int iw = max(min(x2, kx2) - max(x1, kx1), 0);
                    int ih = max(min(y2, ky2) - max(y1, ky1), 0);
                    int I = __mul24(iw, ih); int P = ar + kar;
                    if (I < P && 3 * I > P) dead = true;
                }
                u64 scan = __ballot(!dead);
                while (scan) {
                    int t = (int)__builtin_ctzll(scan);
                    scan &= scan - 1;
                    u64 tb = __shfl(bp, t);
                    if (lane == t) {
                        kArr[kc] = bp;
                        unsigned u = ~(unsigned)(kp2 >> 32);
                        float score = __uint_as_float(u ^ 0x80000000u);
                        out[5*p+0] = score;
                        out[5*p+1] = (float)x1; out[5*p+2] = (float)y1;
                        out[5*p+3] = (float)(x2 - x1); out[5*p+4] = (float)(y2 - y1);
                    }
                    kc++;
                    bool kill = false;
                    if (!dead && lane > t) {
                        int tx1, ty1, tx2, ty2; unpackBox(tb, tx1, ty1, tx2, ty2);
                        int tar = __mul24(tx2 - tx1, ty2 - ty1);
                        int iw = max(min(x2, tx2) - max(x1, tx1), 0);
                        int ih = max(min(y2, ty2) - max(y1, ty1), 0);
                        int I = __mul24(iw, ih); int P = ar + tar;
                        kill = (I < P) && (3 * I > P);
                    }
                    dead = dead || kill;
                    scan &= ~__ballot(dead);
                }
            }
        }
    }
}

extern "C" void kernel_launch(void* const* d_in, const int* in_sizes, int n_in,
                              void* d_out, int out_size, void* d_ws, size_t ws_size,
                              hipStream_t stream) {
    const float* outs0 = (const float*)d_in[0];
    const float* outs1 = (const float*)d_in[1];
    float* out = (float*)d_out;
    char* ws = (char*)d_ws;
    size_t o = 0;
    unsigned* ctrl = (unsigned*)(ws + o); o += 512;
    u64* gKey   = (u64*)(ws + o); o += (size_t)8192 * 8;   // 64 KB
    u64* gBox   = (u64*)(ws + o); o += (size_t)8192 * 8;   // 64 KB
    u64* sKey   = (u64*)(ws + o); o += (size_t)1024 * 8;   // 8 KB
    u64* sBox   = (u64*)(ws + o); o += (size_t)1024 * 8;   // 8 KB
    u64* triG   = (u64*)(ws + o); o += (size_t)6720 * 8;   // 52.5 KB
    u64* fbKey  = (u64*)(ws + o); o += (size_t)8192 * 8;   // 64 KB (fallback)
    u64* fbBoxC = (u64*)(ws + o); o += (size_t)8192 * 8;   // 64 KB (fallback)
    u64* sKey2  = (u64*)(ws + o); o += (size_t)8192 * 8;   // 64 KB (fallback)
    u64* sBox2  = (u64*)(ws + o); o += (size_t)8192 * 8;   // 64 KB (fallback)
    u64* kArr   = (u64*)(ws + o); o += (size_t)8192 * 8;   // 64 KB (fallback)

    hipLaunchKernelGGL(k_all, dim3(NB), dim3(1024), 0, stream,
                       outs0, outs1, out, ctrl, gKey, gBox, sKey, sBox, triG,
                       fbKey, fbBoxC, sKey2, sBox2, kArr);
}